// Round 2
// baseline (529.568 us; speedup 1.0000x reference)
//
#include <hip/hip_runtime.h>
#include <math.h>

// Problem constants
namespace {
constexpr int Bc   = 4;
constexpr int CATT = 8;
constexpr int Dd   = 48;
constexpr int Hh   = 128;
constexpr int Ww   = 256;
constexpr int CF   = 80;
constexpr int EMB  = 64;
constexpr int HEADS = 4;
constexpr int Nn   = Hh * Ww;            // 32768
constexpr float SCALE = 0.25f;           // HEAD_DIM^-0.5, HEAD_DIM=16

// workspace layout (in floats)
constexpr size_t WS_KV    = 0;                                   // B*N*128 = 16,777,216
constexpr size_t WS_DELTA = (size_t)Bc * Nn * 128;               // + B*CATT*N = 1,048,576
constexpr size_t WS_WTKV  = WS_DELTA + (size_t)Bc * CATT * Nn;   // + 80*128
constexpr size_t WS_WTQ   = WS_WTKV + (size_t)CF * 128;          // + 80*64
}  // namespace

// ---------------------------------------------------------------------------
// Kernel 0: transpose weights into c-major layouts for uniform/vector access.
// wtkv[c*128 + o]: o<64 -> Wk[o][c], o>=64 -> Wv[o-64][c]
// wtq [c*64  + e]: Wq[e][c] * SCALE   (pre-scale so scores come out scaled)
// ---------------------------------------------------------------------------
__global__ void prep_weights_k(const float* __restrict__ Wq,
                               const float* __restrict__ Wk,
                               const float* __restrict__ Wv,
                               float* __restrict__ wtkv,
                               float* __restrict__ wtq) {
  const int t = blockIdx.x * blockDim.x + threadIdx.x;
  const int stride = gridDim.x * blockDim.x;
  for (int i = t; i < CF * 128; i += stride) {
    const int c = i >> 7, o = i & 127;
    wtkv[i] = (o < 64) ? Wk[o * CF + c] : Wv[(o - 64) * CF + c];
  }
  for (int i = t; i < CF * 64; i += stride) {
    const int c = i >> 6, e = i & 63;
    wtq[i] = Wq[e * CF + c] * SCALE;
  }
}

// ---------------------------------------------------------------------------
// Kernel 1: K/V projection. Block = 256 threads, 64-pixel tile of one batch.
// feat tile staged in LDS (80x64 = 20 KB). Thread computes 8 outputs x 4 px.
// Output pixel-major: kv[b][n][o], o in [0,128): K channels then V channels.
// ---------------------------------------------------------------------------
__global__ __launch_bounds__(256) void qkv_k(const float* __restrict__ feat,
                                             const float* __restrict__ wtkv,
                                             float* __restrict__ kv) {
  __shared__ float lf[CF][64];
  const int b  = blockIdx.y;
  const int n0 = blockIdx.x * 64;
  const int t  = threadIdx.x;

  const float* fb = feat + (size_t)b * CF * Nn + n0;
  for (int i = t; i < CF * 64; i += 256) {
    const int c = i >> 6, p = i & 63;
    lf[c][p] = fb[(size_t)c * Nn + p];
  }
  __syncthreads();

  const int og = t >> 4;          // output group 0..15 (8 outputs each)
  const int p4 = (t & 15) * 4;    // pixel quad base 0..60

  float acc[8][4];
#pragma unroll
  for (int o = 0; o < 8; ++o)
#pragma unroll
    for (int j = 0; j < 4; ++j) acc[o][j] = 0.f;

  for (int c = 0; c < CF; ++c) {
    const float4 fv = *(const float4*)&lf[c][p4];
    const float fa[4] = {fv.x, fv.y, fv.z, fv.w};
    const float4 wa = *(const float4*)&wtkv[c * 128 + og * 8];
    const float4 wb = *(const float4*)&wtkv[c * 128 + og * 8 + 4];
    const float wv8[8] = {wa.x, wa.y, wa.z, wa.w, wb.x, wb.y, wb.z, wb.w};
#pragma unroll
    for (int o = 0; o < 8; ++o)
#pragma unroll
      for (int j = 0; j < 4; ++j) acc[o][j] = fmaf(wv8[o], fa[j], acc[o][j]);
  }

  float* outb = kv + ((size_t)b * Nn + n0) * 128;
#pragma unroll
  for (int j = 0; j < 4; ++j) {
    const int p = p4 + j;
    const float4 s0 = make_float4(acc[0][j], acc[1][j], acc[2][j], acc[3][j]);
    const float4 s1 = make_float4(acc[4][j], acc[5][j], acc[6][j], acc[7][j]);
    *(float4*)&outb[(size_t)p * 128 + og * 8]     = s0;
    *(float4*)&outb[(size_t)p * 128 + og * 8 + 4] = s1;
  }
}

// ---------------------------------------------------------------------------
// Kernel 2: attention core. One thread per pixel.
// Q computed on the fly (pre-scaled weights). The torch-unfold "mixed" view:
// flat f = w2*64 + e2 = e*9 + widx, so looping (e, widx) with compile-time
// indices covers all (head, w2) score terms exactly once.
// Writes disp-masked delta[b][a][n] (a-major, n contiguous).
// ---------------------------------------------------------------------------
__global__ __launch_bounds__(256) void attn_k(const float* __restrict__ feat,
                                              const float* __restrict__ kvbuf,
                                              const float* __restrict__ wtq,
                                              const float* __restrict__ Wo,
                                              const float* __restrict__ disp,
                                              float* __restrict__ delta) {
  const int b = blockIdx.y;
  const int n = blockIdx.x * 256 + threadIdx.x;
  const int h = n >> 8;    // W == 256
  const int w = n & 255;

  // ---- Q (scaled) ----
  float q[EMB];
#pragma unroll
  for (int e = 0; e < EMB; ++e) q[e] = 0.f;
  {
    const float* fb = feat + (size_t)b * CF * Nn + n;
    for (int c = 0; c < CF; ++c) {
      const float fv = fb[(size_t)c * Nn];
#pragma unroll
      for (int e = 0; e < EMB; ++e) q[e] = fmaf(wtq[c * EMB + e], fv, q[e]);
    }
  }

  const float* kvb = kvbuf + (size_t)b * Nn * 128;

  // ---- scores (already scaled because q is) ----
  float sc[HEADS * 9];
#pragma unroll
  for (int i = 0; i < HEADS * 9; ++i) sc[i] = 0.f;

#pragma unroll
  for (int widx = 0; widx < 9; ++widx) {
    const int di = widx / 3 - 1, dj = widx % 3 - 1;
    const int hh = h + di, ww = w + dj;
    if (hh < 0 || hh >= Hh || ww < 0 || ww >= Ww) continue;  // zero-pad -> 0 contrib
    const float4* kn = (const float4*)(kvb + (size_t)(hh * Ww + ww) * 128);
#pragma unroll
    for (int e4 = 0; e4 < 16; ++e4) {
      const float4 kk = kn[e4];
      const float ka[4] = {kk.x, kk.y, kk.z, kk.w};
#pragma unroll
      for (int j = 0; j < 4; ++j) {
        const int f  = (e4 * 4 + j) * 9 + widx;  // compile-time
        const int w2 = f >> 6;
        const int e2 = f & 63;
        sc[(e2 >> 4) * 9 + w2] = fmaf(q[e2], ka[j], sc[(e2 >> 4) * 9 + w2]);
      }
    }
  }

  // ---- softmax over 9 per head ----
  float probs[HEADS * 9];
#pragma unroll
  for (int hd = 0; hd < HEADS; ++hd) {
    float m = sc[hd * 9];
#pragma unroll
    for (int w2 = 1; w2 < 9; ++w2) m = fmaxf(m, sc[hd * 9 + w2]);
    float s = 0.f;
#pragma unroll
    for (int w2 = 0; w2 < 9; ++w2) {
      const float ev = __expf(sc[hd * 9 + w2] - m);
      probs[hd * 9 + w2] = ev;
      s += ev;
    }
    const float inv = 1.f / s;
#pragma unroll
    for (int w2 = 0; w2 < 9; ++w2) probs[hd * 9 + w2] *= inv;
  }

  // ---- ctx via V (same mixed mapping) ----
  float ctx[EMB];
#pragma unroll
  for (int e = 0; e < EMB; ++e) ctx[e] = 0.f;
#pragma unroll
  for (int widx = 0; widx < 9; ++widx) {
    const int di = widx / 3 - 1, dj = widx % 3 - 1;
    const int hh = h + di, ww = w + dj;
    if (hh < 0 || hh >= Hh || ww < 0 || ww >= Ww) continue;
    const float4* vn = (const float4*)(kvb + (size_t)(hh * Ww + ww) * 128 + 64);
#pragma unroll
    for (int e4 = 0; e4 < 16; ++e4) {
      const float4 vv = vn[e4];
      const float va[4] = {vv.x, vv.y, vv.z, vv.w};
#pragma unroll
      for (int j = 0; j < 4; ++j) {
        const int f  = (e4 * 4 + j) * 9 + widx;
        const int w2 = f >> 6;
        const int e2 = f & 63;
        ctx[e2] = fmaf(probs[(e2 >> 4) * 9 + w2], va[j], ctx[e2]);
      }
    }
  }

  // ---- Wo projection + disp mask ----
  const bool zero = (disp[(size_t)b * Nn + n] >= 2.0f);
  float* dout = delta + (size_t)b * CATT * Nn + n;
#pragma unroll
  for (int a = 0; a < CATT; ++a) {
    float s = 0.f;
#pragma unroll
    for (int e = 0; e < EMB; ++e) s = fmaf(Wo[a * EMB + e], ctx[e], s);
    dout[(size_t)a * Nn] = zero ? 0.f : s;
  }
}

// ---------------------------------------------------------------------------
// Kernel 3: out = attn_vol + delta (broadcast over D). Pure bandwidth pass.
// One float4 per thread, exact grid. delta (4 MB) stays L2-resident.
// ---------------------------------------------------------------------------
__global__ __launch_bounds__(256) void add_k(const float* __restrict__ av,
                                             const float* __restrict__ delta,
                                             float* __restrict__ out) {
  const unsigned i4 = blockIdx.x * 256u + threadIdx.x;  // < 12,582,912
  const unsigned n4 = i4 & 8191u;          // N/4 = 8192 float4 per (b,c,d) row-plane
  const unsigned t2 = i4 >> 13;            // b*CATT*D + c*D + d, < 1536
  const unsigned bc = t2 / 48u;            // b*CATT + c, 0..31
  const float4 a  = ((const float4*)av)[i4];
  const float4 dl = ((const float4*)delta)[(size_t)bc * 8192u + n4];
  float4 r;
  r.x = a.x + dl.x;
  r.y = a.y + dl.y;
  r.z = a.z + dl.z;
  r.w = a.w + dl.w;
  ((float4*)out)[i4] = r;
}

// ---------------------------------------------------------------------------
extern "C" void kernel_launch(void* const* d_in, const int* in_sizes, int n_in,
                              void* d_out, int out_size, void* d_ws, size_t ws_size,
                              hipStream_t stream) {
  const float* attn_vol = (const float*)d_in[0];
  const float* feat     = (const float*)d_in[1];
  const float* disp     = (const float*)d_in[2];
  const float* Wq       = (const float*)d_in[3];
  const float* Wk       = (const float*)d_in[4];
  const float* Wv       = (const float*)d_in[5];
  const float* Wo       = (const float*)d_in[6];
  float* out            = (float*)d_out;

  float* ws    = (float*)d_ws;
  float* kv    = ws + WS_KV;
  float* delta = ws + WS_DELTA;
  float* wtkv  = ws + WS_WTKV;
  float* wtq   = ws + WS_WTQ;

  hipLaunchKernelGGL(prep_weights_k, dim3(40), dim3(256), 0, stream,
                     Wq, Wk, Wv, wtkv, wtq);
  hipLaunchKernelGGL(qkv_k, dim3(Nn / 64, Bc), dim3(256), 0, stream,
                     feat, wtkv, kv);
  hipLaunchKernelGGL(attn_k, dim3(Nn / 256, Bc), dim3(256), 0, stream,
                     feat, kv, wtq, Wo, disp, delta);
  const int nf4 = out_size / 4;  // 12,582,912
  hipLaunchKernelGGL(add_k, dim3(nf4 / 256), dim3(256), 0, stream,
                     attn_vol, delta, out);
}

// Round 3
// 488.830 us; speedup vs baseline: 1.0833x; 1.0833x over previous
//
#include <hip/hip_runtime.h>
#include <math.h>

namespace {
constexpr int Bc   = 4;
constexpr int CATT = 8;
constexpr int Hh   = 128;
constexpr int Ww   = 256;
constexpr int CF   = 80;
constexpr int EMB  = 64;
constexpr int Nn   = Hh * Ww;            // 32768
constexpr float SCALE = 0.25f;

// ---- new padded-plane layout ----
constexpr int ROWP  = 264;               // 4 left pad + 256 + 4 right pad
constexpr int PLANE = 130 * ROWP;        // 34320 floats per plane (1 halo row top/bot)
constexpr size_t WS_KVQ   = 0;                                    // 4*192*PLANE = 26,357,760
constexpr size_t WS_DELTA = (size_t)Bc * 192 * PLANE;             // + 1,048,576
constexpr size_t WS_WT    = WS_DELTA + (size_t)Bc * CATT * Nn;    // + 80*192
constexpr size_t WS_WOT   = WS_WT + (size_t)CF * 192;             // + 512
constexpr size_t WS_END   = WS_WOT + 512;
constexpr size_t NEED_BYTES = WS_END * 4;

// ---- old (fallback) layout ----
constexpr size_t OWS_KV    = 0;                                   // B*N*128
constexpr size_t OWS_DELTA = (size_t)Bc * Nn * 128;
constexpr size_t OWS_WTKV  = OWS_DELTA + (size_t)Bc * CATT * Nn;
constexpr size_t OWS_WTQ   = OWS_WTKV + (size_t)CF * 128;
}  // namespace

// ===========================================================================
// NEW PATH
// ===========================================================================

// prep: wt[c][192] (Q prescaled | K | V), Wot[e][8] = Wo[a][e], zero kvq halos
__global__ void prep_new_k(const float* __restrict__ Wq,
                           const float* __restrict__ Wk,
                           const float* __restrict__ Wv,
                           const float* __restrict__ Wo,
                           float* __restrict__ wt,
                           float* __restrict__ wot,
                           float* __restrict__ kvq) {
  const int t = blockIdx.x * blockDim.x + threadIdx.x;
  const int stride = gridDim.x * blockDim.x;
  for (int i = t; i < CF * 192; i += stride) {
    const int c = i / 192, o = i % 192;
    float v;
    if (o < 64)       v = Wq[o * CF + c] * SCALE;
    else if (o < 128) v = Wk[(o - 64) * CF + c];
    else              v = Wv[(o - 128) * CF + c];
    wt[i] = v;
  }
  for (int i = t; i < 512; i += stride) {
    const int e = i >> 3, a = i & 7;
    wot[i] = Wo[a * EMB + e];
  }
  // halo: per plane 1552 elems: row0 (264), row129 (264), rows1..128 cols {0..3,260..263}
  const int HALO = 1552;
  for (int i = t; i < Bc * 192 * HALO; i += stride) {
    const int plane = i / HALO;
    const int r = i % HALO;
    int row, col;
    if (r < 264)        { row = 0;   col = r; }
    else if (r < 528)   { row = 129; col = r - 264; }
    else {
      const int rr = r - 528;
      row = (rr >> 3) + 1;
      const int c8 = rr & 7;
      col = (c8 < 4) ? c8 : (260 + c8 - 4);
    }
    kvq[(size_t)plane * PLANE + row * ROWP + col] = 0.f;
  }
}

// QKV projection into padded planes. Block=256, 64-pixel row chunk.
// Thread: 12 outputs x 4 pixels.
__global__ __launch_bounds__(256) void qkv_new_k(const float* __restrict__ feat,
                                                 const float* __restrict__ wt,
                                                 float* __restrict__ kvq) {
  __shared__ float lf[CF][64];
  const int b  = blockIdx.y;
  const int n0 = blockIdx.x * 64;
  const int t  = threadIdx.x;

  const float* fb = feat + (size_t)b * CF * Nn + n0;
  for (int i = t; i < CF * 64; i += 256) {
    const int c = i >> 6, p = i & 63;
    lf[c][p] = fb[(size_t)c * Nn + p];
  }
  __syncthreads();

  const int og = t >> 4;          // 16 groups of 12 outputs
  const int p4 = (t & 15) * 4;

  float acc[12][4];
#pragma unroll
  for (int o = 0; o < 12; ++o)
#pragma unroll
    for (int j = 0; j < 4; ++j) acc[o][j] = 0.f;

  for (int c = 0; c < CF; ++c) {
    const float4 fv = *(const float4*)&lf[c][p4];
    const float fa[4] = {fv.x, fv.y, fv.z, fv.w};
    const float4 w0 = *(const float4*)&wt[c * 192 + og * 12];
    const float4 w1 = *(const float4*)&wt[c * 192 + og * 12 + 4];
    const float4 w2 = *(const float4*)&wt[c * 192 + og * 12 + 8];
    const float wv12[12] = {w0.x, w0.y, w0.z, w0.w, w1.x, w1.y, w1.z, w1.w,
                            w2.x, w2.y, w2.z, w2.w};
#pragma unroll
    for (int o = 0; o < 12; ++o)
#pragma unroll
      for (int j = 0; j < 4; ++j) acc[o][j] = fmaf(wv12[o], fa[j], acc[o][j]);
  }

  const int h = n0 >> 8, w0c = n0 & 255;
  float* bbase = kvq + (size_t)b * 192 * PLANE;
  const int rowoff = (h + 1) * ROWP + (w0c + 4) + p4;
#pragma unroll
  for (int o = 0; o < 12; ++o) {
    const int oo = og * 12 + o;
    *(float4*)&bbase[(size_t)oo * PLANE + rowoff] =
        make_float4(acc[o][0], acc[o][1], acc[o][2], acc[o][3]);
  }
}

// attention core for one head (wave-uniform HD -> compile-time offsets)
template <int HD>
__device__ __forceinline__ void attn_core(const float* __restrict__ kb, int coff,
                                          const float* __restrict__ lwot,
                                          float* __restrict__ part) {
  float q16[16];
#pragma unroll
  for (int i = 0; i < 16; ++i)
    q16[i] = kb[(size_t)(HD * 16 + i) * PLANE + coff];

  float sc[9];
#pragma unroll
  for (int w2 = 0; w2 < 9; ++w2) {
    float s = 0.f;
#pragma unroll
    for (int i = 0; i < 16; ++i) {
      const int f = w2 * 64 + HD * 16 + i;       // compile-time after unroll
      const int e = f / 9, widx = f % 9;
      const int D = (widx / 3 - 1) * ROWP + (widx % 3 - 1);
      s = fmaf(q16[i], kb[(size_t)(64 + e) * PLANE + coff + D], s);
    }
    sc[w2] = s;
  }

  float m = sc[0];
#pragma unroll
  for (int w2 = 1; w2 < 9; ++w2) m = fmaxf(m, sc[w2]);
  float probs[9], ssum = 0.f;
#pragma unroll
  for (int w2 = 0; w2 < 9; ++w2) {
    probs[w2] = __expf(sc[w2] - m);
    ssum += probs[w2];
  }
  const float inv = 1.f / ssum;
#pragma unroll
  for (int w2 = 0; w2 < 9; ++w2) probs[w2] *= inv;

  float ctx[16];
#pragma unroll
  for (int i = 0; i < 16; ++i) {
    float c = 0.f;
#pragma unroll
    for (int w2 = 0; w2 < 9; ++w2) {
      const int f = w2 * 64 + HD * 16 + i;
      const int e = f / 9, widx = f % 9;
      const int D = (widx / 3 - 1) * ROWP + (widx % 3 - 1);
      c = fmaf(probs[w2], kb[(size_t)(128 + e) * PLANE + coff + D], c);
    }
    ctx[i] = c;
  }

#pragma unroll
  for (int a = 0; a < 8; ++a) {
    float p = 0.f;
#pragma unroll
    for (int i = 0; i < 16; ++i)
      p = fmaf(lwot[(HD * 16 + i) * 8 + a], ctx[i], p);
    part[a] = p;
  }
}

// Block=256 (4 waves), wave = head, lanes = 64 consecutive pixels of one row.
__global__ __launch_bounds__(256) void attn_new_k(const float* __restrict__ kvq,
                                                  const float* __restrict__ wot,
                                                  const float* __restrict__ disp,
                                                  float* __restrict__ delta) {
  __shared__ float lwot[512];
  __shared__ float lpart[4 * 576];   // [hd][px*9 + a], stride 9 kills bank conflicts
  const int b = blockIdx.y;
  const int t = threadIdx.x;
  for (int i = t; i < 512; i += 256) lwot[i] = wot[i];
  __syncthreads();

  const int hd = t >> 6, lane = t & 63;
  const int n = blockIdx.x * 64 + lane;
  const int h = n >> 8, w = n & 255;
  const int coff = (h + 1) * ROWP + (w + 4);
  const float* kb = kvq + (size_t)b * 192 * PLANE;

  float part[8];
  switch (hd) {
    case 0: attn_core<0>(kb, coff, lwot, part); break;
    case 1: attn_core<1>(kb, coff, lwot, part); break;
    case 2: attn_core<2>(kb, coff, lwot, part); break;
    default: attn_core<3>(kb, coff, lwot, part); break;
  }
#pragma unroll
  for (int a = 0; a < 8; ++a) lpart[hd * 576 + lane * 9 + a] = part[a];
  __syncthreads();

  const int px = t & 63, ag = t >> 6;
  const int nn = blockIdx.x * 64 + px;
  const bool zero = disp[(size_t)b * Nn + nn] >= 2.0f;
  float* dout = delta + (size_t)b * CATT * Nn + nn;
#pragma unroll
  for (int k = 0; k < 2; ++k) {
    const int a = ag * 2 + k;
    const float s = lpart[0 * 576 + px * 9 + a] + lpart[1 * 576 + px * 9 + a] +
                    lpart[2 * 576 + px * 9 + a] + lpart[3 * 576 + px * 9 + a];
    dout[(size_t)a * Nn] = zero ? 0.f : s;
  }
}

// ===========================================================================
// OLD PATH (fallback if ws too small) — identical to the passing R2 kernels
// ===========================================================================
__global__ void prep_weights_k(const float* __restrict__ Wq,
                               const float* __restrict__ Wk,
                               const float* __restrict__ Wv,
                               float* __restrict__ wtkv,
                               float* __restrict__ wtq) {
  const int t = blockIdx.x * blockDim.x + threadIdx.x;
  const int stride = gridDim.x * blockDim.x;
  for (int i = t; i < CF * 128; i += stride) {
    const int c = i >> 7, o = i & 127;
    wtkv[i] = (o < 64) ? Wk[o * CF + c] : Wv[(o - 64) * CF + c];
  }
  for (int i = t; i < CF * 64; i += stride) {
    const int c = i >> 6, e = i & 63;
    wtq[i] = Wq[e * CF + c] * SCALE;
  }
}

__global__ __launch_bounds__(256) void qkv_k(const float* __restrict__ feat,
                                             const float* __restrict__ wtkv,
                                             float* __restrict__ kv) {
  __shared__ float lf[CF][64];
  const int b  = blockIdx.y;
  const int n0 = blockIdx.x * 64;
  const int t  = threadIdx.x;
  const float* fb = feat + (size_t)b * CF * Nn + n0;
  for (int i = t; i < CF * 64; i += 256) {
    const int c = i >> 6, p = i & 63;
    lf[c][p] = fb[(size_t)c * Nn + p];
  }
  __syncthreads();
  const int og = t >> 4;
  const int p4 = (t & 15) * 4;
  float acc[8][4];
#pragma unroll
  for (int o = 0; o < 8; ++o)
#pragma unroll
    for (int j = 0; j < 4; ++j) acc[o][j] = 0.f;
  for (int c = 0; c < CF; ++c) {
    const float4 fv = *(const float4*)&lf[c][p4];
    const float fa[4] = {fv.x, fv.y, fv.z, fv.w};
    const float4 wa = *(const float4*)&wtkv[c * 128 + og * 8];
    const float4 wb = *(const float4*)&wtkv[c * 128 + og * 8 + 4];
    const float wv8[8] = {wa.x, wa.y, wa.z, wa.w, wb.x, wb.y, wb.z, wb.w};
#pragma unroll
    for (int o = 0; o < 8; ++o)
#pragma unroll
      for (int j = 0; j < 4; ++j) acc[o][j] = fmaf(wv8[o], fa[j], acc[o][j]);
  }
  float* outb = kv + ((size_t)b * Nn + n0) * 128;
#pragma unroll
  for (int j = 0; j < 4; ++j) {
    const int p = p4 + j;
    *(float4*)&outb[(size_t)p * 128 + og * 8] =
        make_float4(acc[0][j], acc[1][j], acc[2][j], acc[3][j]);
    *(float4*)&outb[(size_t)p * 128 + og * 8 + 4] =
        make_float4(acc[4][j], acc[5][j], acc[6][j], acc[7][j]);
  }
}

__global__ __launch_bounds__(256) void attn_k(const float* __restrict__ feat,
                                              const float* __restrict__ kvbuf,
                                              const float* __restrict__ wtq,
                                              const float* __restrict__ Wo,
                                              const float* __restrict__ disp,
                                              float* __restrict__ delta) {
  const int b = blockIdx.y;
  const int n = blockIdx.x * 256 + threadIdx.x;
  const int h = n >> 8;
  const int w = n & 255;
  float q[EMB];
#pragma unroll
  for (int e = 0; e < EMB; ++e) q[e] = 0.f;
  {
    const float* fb = feat + (size_t)b * CF * Nn + n;
    for (int c = 0; c < CF; ++c) {
      const float fv = fb[(size_t)c * Nn];
#pragma unroll
      for (int e = 0; e < EMB; ++e) q[e] = fmaf(wtq[c * EMB + e], fv, q[e]);
    }
  }
  const float* kvb = kvbuf + (size_t)b * Nn * 128;
  float sc[36];
#pragma unroll
  for (int i = 0; i < 36; ++i) sc[i] = 0.f;
#pragma unroll
  for (int widx = 0; widx < 9; ++widx) {
    const int di = widx / 3 - 1, dj = widx % 3 - 1;
    const int hh = h + di, ww = w + dj;
    if (hh < 0 || hh >= Hh || ww < 0 || ww >= Ww) continue;
    const float4* kn = (const float4*)(kvb + (size_t)(hh * Ww + ww) * 128);
#pragma unroll
    for (int e4 = 0; e4 < 16; ++e4) {
      const float4 kk = kn[e4];
      const float ka[4] = {kk.x, kk.y, kk.z, kk.w};
#pragma unroll
      for (int j = 0; j < 4; ++j) {
        const int f = (e4 * 4 + j) * 9 + widx;
        const int w2 = f >> 6, e2 = f & 63;
        sc[(e2 >> 4) * 9 + w2] = fmaf(q[e2], ka[j], sc[(e2 >> 4) * 9 + w2]);
      }
    }
  }
  float probs[36];
#pragma unroll
  for (int hdx = 0; hdx < 4; ++hdx) {
    float m = sc[hdx * 9];
#pragma unroll
    for (int w2 = 1; w2 < 9; ++w2) m = fmaxf(m, sc[hdx * 9 + w2]);
    float s = 0.f;
#pragma unroll
    for (int w2 = 0; w2 < 9; ++w2) {
      const float ev = __expf(sc[hdx * 9 + w2] - m);
      probs[hdx * 9 + w2] = ev;
      s += ev;
    }
    const float inv = 1.f / s;
#pragma unroll
    for (int w2 = 0; w2 < 9; ++w2) probs[hdx * 9 + w2] *= inv;
  }
  float ctx[EMB];
#pragma unroll
  for (int e = 0; e < EMB; ++e) ctx[e] = 0.f;
#pragma unroll
  for (int widx = 0; widx < 9; ++widx) {
    const int di = widx / 3 - 1, dj = widx % 3 - 1;
    const int hh = h + di, ww = w + dj;
    if (hh < 0 || hh >= Hh || ww < 0 || ww >= Ww) continue;
    const float4* vn = (const float4*)(kvb + (size_t)(hh * Ww + ww) * 128 + 64);
#pragma unroll
    for (int e4 = 0; e4 < 16; ++e4) {
      const float4 vv = vn[e4];
      const float va[4] = {vv.x, vv.y, vv.z, vv.w};
#pragma unroll
      for (int j = 0; j < 4; ++j) {
        const int f = (e4 * 4 + j) * 9 + widx;
        const int w2 = f >> 6, e2 = f & 63;
        ctx[e2] = fmaf(probs[(e2 >> 4) * 9 + w2], va[j], ctx[e2]);
      }
    }
  }
  const bool zero = (disp[(size_t)b * Nn + n] >= 2.0f);
  float* dout = delta + (size_t)b * CATT * Nn + n;
#pragma unroll
  for (int a = 0; a < CATT; ++a) {
    float s = 0.f;
#pragma unroll
    for (int e = 0; e < EMB; ++e) s = fmaf(Wo[a * EMB + e], ctx[e], s);
    dout[(size_t)a * Nn] = zero ? 0.f : s;
  }
}

// ===========================================================================
// shared final add
// ===========================================================================
__global__ __launch_bounds__(256) void add_k(const float* __restrict__ av,
                                             const float* __restrict__ delta,
                                             float* __restrict__ out) {
  const unsigned i4 = blockIdx.x * 256u + threadIdx.x;
  const unsigned n4 = i4 & 8191u;
  const unsigned t2 = i4 >> 13;
  const unsigned bc = t2 / 48u;
  const float4 a  = ((const float4*)av)[i4];
  const float4 dl = ((const float4*)delta)[(size_t)bc * 8192u + n4];
  ((float4*)out)[i4] = make_float4(a.x + dl.x, a.y + dl.y, a.z + dl.z, a.w + dl.w);
}

// ===========================================================================
extern "C" void kernel_launch(void* const* d_in, const int* in_sizes, int n_in,
                              void* d_out, int out_size, void* d_ws, size_t ws_size,
                              hipStream_t stream) {
  const float* attn_vol = (const float*)d_in[0];
  const float* feat     = (const float*)d_in[1];
  const float* disp     = (const float*)d_in[2];
  const float* Wq       = (const float*)d_in[3];
  const float* Wk       = (const float*)d_in[4];
  const float* Wv       = (const float*)d_in[5];
  const float* Wo       = (const float*)d_in[6];
  float* out            = (float*)d_out;
  float* ws             = (float*)d_ws;
  const int nf4 = out_size / 4;

  if (ws_size >= NEED_BYTES) {
    float* kvq   = ws + WS_KVQ;
    float* delta = ws + WS_DELTA;
    float* wt    = ws + WS_WT;
    float* wot   = ws + WS_WOT;
    hipLaunchKernelGGL(prep_new_k, dim3(512), dim3(256), 0, stream,
                       Wq, Wk, Wv, Wo, wt, wot, kvq);
    hipLaunchKernelGGL(qkv_new_k, dim3(Nn / 64, Bc), dim3(256), 0, stream,
                       feat, wt, kvq);
    hipLaunchKernelGGL(attn_new_k, dim3(Nn / 64, Bc), dim3(256), 0, stream,
                       kvq, wot, disp, delta);
    hipLaunchKernelGGL(add_k, dim3(nf4 / 256), dim3(256), 0, stream,
                       attn_vol, delta, out);
  } else {
    float* kv    = ws + OWS_KV;
    float* delta = ws + OWS_DELTA;
    float* wtkv  = ws + OWS_WTKV;
    float* wtq   = ws + OWS_WTQ;
    hipLaunchKernelGGL(prep_weights_k, dim3(40), dim3(256), 0, stream,
                       Wq, Wk, Wv, wtkv, wtq);
    hipLaunchKernelGGL(qkv_k, dim3(Nn / 64, Bc), dim3(256), 0, stream,
                       feat, wtkv, kv);
    hipLaunchKernelGGL(attn_k, dim3(Nn / 256, Bc), dim3(256), 0, stream,
                       feat, kv, wtq, Wo, disp, delta);
    hipLaunchKernelGGL(add_k, dim3(nf4 / 256), dim3(256), 0, stream,
                       attn_vol, delta, out);
  }
}